// Round 1
// baseline (537.395 us; speedup 1.0000x reference)
//
#include <hip/hip_runtime.h>

constexpr int B = 8, S = 2048, E = 1024, H = 64;
constexpr float SCALE = 0.03125f; // 1/sqrt(1024)

// ---------------- QKV projection ----------------
// grid: (B*S)/32 blocks, 256 threads. Thread t: h = t&63, row-group = t>>6
// (8 consecutive rows each). x tile (32x64) staged in LDS; W streamed from
// L2 (768 KB total, heavily reused).
__global__ __launch_bounds__(256) void qkv_kernel(
    const float* __restrict__ x, const float* __restrict__ Wq,
    const float* __restrict__ Wk, const float* __restrict__ Wv,
    float* __restrict__ q, float* __restrict__ k, float* __restrict__ v) {
  __shared__ float xs[32][64];
  const int h = threadIdx.x & 63;
  const int rg = threadIdx.x >> 6;
  const long row0 = (long)blockIdx.x * 32;
  float accq[8], acck[8], accv[8];
#pragma unroll
  for (int i = 0; i < 8; ++i) { accq[i] = 0.f; acck[i] = 0.f; accv[i] = 0.f; }

  for (int e0 = 0; e0 < E; e0 += 64) {
    __syncthreads();
#pragma unroll
    for (int it = 0; it < 2; ++it) {
      int idx = threadIdx.x + it * 256;   // 0..511 float4 slots
      int r = idx >> 4, c = idx & 15;
      float4 t = ((const float4*)(x + (row0 + r) * E + e0))[c];
      ((float4*)&xs[r][0])[c] = t;
    }
    __syncthreads();
    const float* wqp = Wq + (long)e0 * H + h;
    const float* wkp = Wk + (long)e0 * H + h;
    const float* wvp = Wv + (long)e0 * H + h;
#pragma unroll 4
    for (int e = 0; e < 64; e += 4) {
      float4 xv[8];
#pragma unroll
      for (int r = 0; r < 8; ++r)
        xv[r] = *(const float4*)&xs[rg * 8 + r][e];   // broadcast b128
#pragma unroll
      for (int u = 0; u < 4; ++u) {
        float wq = wqp[(e + u) * H];
        float wk = wkp[(e + u) * H];
        float wv = wvp[(e + u) * H];
#pragma unroll
        for (int r = 0; r < 8; ++r) {
          float xe = (&xv[r].x)[u];
          accq[r] = fmaf(xe, wq, accq[r]);
          acck[r] = fmaf(xe, wk, acck[r]);
          accv[r] = fmaf(xe, wv, accv[r]);
        }
      }
    }
  }
#pragma unroll
  for (int r = 0; r < 8; ++r) {
    long orow = row0 + rg * 8 + r;
    q[orow * H + h] = accq[r];
    k[orow * H + h] = acck[r];
    v[orow * H + h] = accv[r];
  }
}

// ---------------- causal flash attention ----------------
// grid: B * (S/32) blocks, 256 threads (4 waves). Query tile = 32 rows.
// Wave w owns rows {w, w+4, ..., w+28}; within a wave, lane = j (score
// phase) or lane = h (PV phase). m/l/alpha stay in registers (wave-uniform
// after the 64-lane shuffle reductions).
__global__ __launch_bounds__(256) void attn_kernel(
    const float* __restrict__ q, const float* __restrict__ k,
    const float* __restrict__ v, float* __restrict__ out) {
  __shared__ float qs[32][64];
  __shared__ float ks[64][65];   // +1 pad: lane-row reads -> 2-way (free)
  __shared__ float vs[64][65];
  __shared__ float ps[32][64];
  const int lane = threadIdx.x & 63;
  const int rs = threadIdx.x >> 6;
  const int qt = blockIdx.x & 63;       // S/32 = 64 tiles
  const int b = blockIdx.x >> 6;
  const float* qb = q + (long)b * S * H;
  const float* kb = k + (long)b * S * H;
  const float* vb = v + (long)b * S * H;

  // stage q tile, pre-scaled by E^-0.5
#pragma unroll
  for (int it = 0; it < 2; ++it) {
    int idx = threadIdx.x + it * 256;
    int r = idx >> 4, c = idx & 15;
    float4 t = ((const float4*)(qb + (qt * 32 + r) * H))[c];
    t.x *= SCALE; t.y *= SCALE; t.z *= SCALE; t.w *= SCALE;
    ((float4*)&qs[r][0])[c] = t;
  }

  float m[8], l[8], o[8], al[8];
#pragma unroll
  for (int i = 0; i < 8; ++i) { m[i] = -__builtin_inff(); l[i] = 0.f; o[i] = 0.f; }

  const int kt_max = (qt * 32 + 31) >> 6;
  for (int kt = 0; kt <= kt_max; ++kt) {
    __syncthreads();   // prior tile fully consumed before overwrite
#pragma unroll
    for (int it = 0; it < 4; ++it) {
      int idx = threadIdx.x + it * 256;   // 0..1023 float4 slots
      int r = idx >> 4, c4 = idx & 15;
      float4 tk = ((const float4*)(kb + ((long)kt * 64 + r) * H))[c4];
      float4 tv = ((const float4*)(vb + ((long)kt * 64 + r) * H))[c4];
      ks[r][c4 * 4 + 0] = tk.x; ks[r][c4 * 4 + 1] = tk.y;
      ks[r][c4 * 4 + 2] = tk.z; ks[r][c4 * 4 + 3] = tk.w;
      vs[r][c4 * 4 + 0] = tv.x; vs[r][c4 * 4 + 1] = tv.y;
      vs[r][c4 * 4 + 2] = tv.z; vs[r][c4 * 4 + 3] = tv.w;
    }
    __syncthreads();

    // ---- scores: s[i] = q[row_i] . k[lane] ----
    float s[8];
#pragma unroll
    for (int i = 0; i < 8; ++i) s[i] = 0.f;
    for (int hh = 0; hh < 64; ++hh) {
      float kv = ks[lane][hh];
#pragma unroll
      for (int i = 0; i < 8; ++i)
        s[i] = fmaf(qs[rs + 4 * i][hh], kv, s[i]);   // q read broadcasts
    }
    if (kt == kt_max) {   // only the diagonal tile needs masking (QT=32)
#pragma unroll
      for (int i = 0; i < 8; ++i) {
        int gq = qt * 32 + rs + 4 * i;
        int gk = kt * 64 + lane;
        if (gk > gq) s[i] = -__builtin_inff();
      }
    }
    // ---- online softmax (per-row, 64-lane shuffle reductions) ----
#pragma unroll
    for (int i = 0; i < 8; ++i) {
      float sm = s[i];
#pragma unroll
      for (int off = 32; off > 0; off >>= 1)
        sm = fmaxf(sm, __shfl_xor(sm, off));
      float mnew = fmaxf(m[i], sm);
      float pj = __expf(s[i] - mnew);      // masked lanes -> 0
      float alpha = __expf(m[i] - mnew);   // first tile: exp(-inf) = 0
      float sum = pj;
#pragma unroll
      for (int off = 32; off > 0; off >>= 1)
        sum += __shfl_xor(sum, off);
      l[i] = l[i] * alpha + sum;
      m[i] = mnew;
      al[i] = alpha;
      ps[rs + 4 * i][lane] = pj;   // same wave reads these rows in PV
    }
    // ---- PV: o[i] = o[i]*alpha + P[row_i,:] . V[:,lane] ----
#pragma unroll
    for (int i = 0; i < 8; ++i) o[i] *= al[i];
    for (int jj = 0; jj < 64; ++jj) {
      float vv = vs[jj][lane];
#pragma unroll
      for (int i = 0; i < 8; ++i)
        o[i] = fmaf(ps[rs + 4 * i][jj], vv, o[i]);   // p read broadcasts
    }
  }

#pragma unroll
  for (int i = 0; i < 8; ++i) {
    int gq = qt * 32 + rs + 4 * i;
    out[((long)b * S + gq) * H + lane] = o[i] / l[i];
  }
}

extern "C" void kernel_launch(void* const* d_in, const int* in_sizes, int n_in,
                              void* d_out, int out_size, void* d_ws, size_t ws_size,
                              hipStream_t stream) {
  const float* x  = (const float*)d_in[0];
  const float* Wq = (const float*)d_in[1];
  const float* Wk = (const float*)d_in[2];
  const float* Wv = (const float*)d_in[3];
  float* out = (float*)d_out;
  float* q = (float*)d_ws;                   // 3 x 4 MB scratch
  float* k = q + (size_t)B * S * H;
  float* v = k + (size_t)B * S * H;
  qkv_kernel<<<dim3((B * S) / 32), dim3(256), 0, stream>>>(x, Wq, Wk, Wv, q, k, v);
  attn_kernel<<<dim3(B * (S / 32)), dim3(256), 0, stream>>>(q, k, v, out);
}

// Round 2
// 187.954 us; speedup vs baseline: 2.8592x; 2.8592x over previous
//
#include <hip/hip_runtime.h>

constexpr int Bn = 8, S = 2048, E = 1024, H = 64;
constexpr float SCALE = 0.03125f;     // E^-0.5
constexpr float LOG2E = 1.44269504f;

typedef __attribute__((ext_vector_type(8))) short short8;  // 8 bf16 (4 VGPRs)
typedef __attribute__((ext_vector_type(4))) float f32x4;   // MFMA C/D

__device__ __forceinline__ unsigned short f2bf(float f) {
  unsigned u = __builtin_bit_cast(unsigned, f);
  u += 0x7fffu + ((u >> 16) & 1u);    // RNE
  return (unsigned short)(u >> 16);
}
__device__ __forceinline__ ushort4 f4bf(float4 f) {
  return make_ushort4(f2bf(f.x), f2bf(f.y), f2bf(f.z), f2bf(f.w));
}

// ---------- W [1024][64] fp32 -> WT3 [3][64][1024] bf16 ----------
__global__ __launch_bounds__(256) void wtrans_kernel(
    const float* __restrict__ Wq, const float* __restrict__ Wk,
    const float* __restrict__ Wv, unsigned short* __restrict__ WT3) {
  __shared__ unsigned short tb[64][72];
  const int m = blockIdx.x >> 4;            // 3 mats x 16 e-tiles
  const int e0 = (blockIdx.x & 15) * 64;
  const float* W = (m == 0) ? Wq : (m == 1) ? Wk : Wv;
  const int t = threadIdx.x;
#pragma unroll
  for (int it = 0; it < 4; ++it) {
    int idx = t + it * 256;
    int r = idx >> 4, c4 = idx & 15;
    float4 f = ((const float4*)(W + (long)(e0 + r) * H))[c4];
    *(ushort4*)&tb[r][c4 * 4] = f4bf(f);
  }
  __syncthreads();
#pragma unroll
  for (int it = 0; it < 4; ++it) {
    int idx = t + it * 256;
    int h = idx >> 4, e4 = idx & 15;
    ushort4 u = make_ushort4(tb[e4 * 4 + 0][h], tb[e4 * 4 + 1][h],
                             tb[e4 * 4 + 2][h], tb[e4 * 4 + 3][h]);
    ((ushort4*)(WT3 + (long)(m * 64 + h) * E + e0))[e4] = u;
  }
}

// ---------- QKV: [16384x1024] @ [1024x64] x3, bf16 MFMA ----------
__global__ __launch_bounds__(256) void qkv_kernel(
    const float* __restrict__ x, const unsigned short* __restrict__ WT3,
    float* __restrict__ q, float* __restrict__ k, float* __restrict__ v) {
  __shared__ unsigned short xs[64][72];       // rows=seq, cols=e (pad->16B rows)
  __shared__ unsigned short wt[3][64][72];    // rows=h,   cols=e
  const int t = threadIdx.x;
  const int w = t >> 6, lane = t & 63, l15 = lane & 15, g = lane >> 4;
  const long row0 = (long)blockIdx.x * 64;

  f32x4 acc[3][4];
#pragma unroll
  for (int mm = 0; mm < 3; ++mm)
#pragma unroll
    for (int hc = 0; hc < 4; ++hc) acc[mm][hc] = f32x4{0.f, 0.f, 0.f, 0.f};

  float4 px[4];
  ushort4 pw[12];
  // prologue: chunk 0 -> regs -> LDS
#pragma unroll
  for (int it = 0; it < 4; ++it) {
    int idx = t + it * 256;
    px[it] = ((const float4*)(x + (row0 + (idx >> 4)) * E))[idx & 15];
  }
#pragma unroll
  for (int it = 0; it < 12; ++it) {
    int idx = t + it * 256;
    int mm = idx >> 10, rem = idx & 1023;
    pw[it] = ((const ushort4*)(WT3 + (long)(mm * 64 + (rem >> 4)) * E))[rem & 15];
  }
#pragma unroll
  for (int it = 0; it < 4; ++it) {
    int idx = t + it * 256;
    *(ushort4*)&xs[idx >> 4][(idx & 15) * 4] = f4bf(px[it]);
  }
#pragma unroll
  for (int it = 0; it < 12; ++it) {
    int idx = t + it * 256;
    int mm = idx >> 10, rem = idx & 1023;
    *(ushort4*)&wt[mm][rem >> 4][(rem & 15) * 4] = pw[it];
  }

  for (int c = 0; c < 16; ++c) {          // 16 chunks of 64 e
    __syncthreads();                       // LDS writes visible
    if (c < 15) {                          // prefetch next chunk (latency hidden)
      int e0 = (c + 1) * 64;
#pragma unroll
      for (int it = 0; it < 4; ++it) {
        int idx = t + it * 256;
        px[it] = ((const float4*)(x + (row0 + (idx >> 4)) * E + e0))[idx & 15];
      }
#pragma unroll
      for (int it = 0; it < 12; ++it) {
        int idx = t + it * 256;
        int mm = idx >> 10, rem = idx & 1023;
        pw[it] = ((const ushort4*)(WT3 + (long)(mm * 64 + (rem >> 4)) * E + e0))[rem & 15];
      }
    }
#pragma unroll
    for (int kh = 0; kh < 2; ++kh) {
      short8 a = *(const short8*)&xs[w * 16 + l15][kh * 32 + g * 8];
#pragma unroll
      for (int mm = 0; mm < 3; ++mm)
#pragma unroll
        for (int hc = 0; hc < 4; ++hc) {
          short8 b = *(const short8*)&wt[mm][hc * 16 + l15][kh * 32 + g * 8];
          acc[mm][hc] = __builtin_amdgcn_mfma_f32_16x16x32_bf16(a, b, acc[mm][hc], 0, 0, 0);
        }
    }
    __syncthreads();                       // all reads of LDS done
    if (c < 15) {
#pragma unroll
      for (int it = 0; it < 4; ++it) {
        int idx = t + it * 256;
        *(ushort4*)&xs[idx >> 4][(idx & 15) * 4] = f4bf(px[it]);
      }
#pragma unroll
      for (int it = 0; it < 12; ++it) {
        int idx = t + it * 256;
        int mm = idx >> 10, rem = idx & 1023;
        *(ushort4*)&wt[mm][rem >> 4][(rem & 15) * 4] = pw[it];
      }
    }
  }
#pragma unroll
  for (int mm = 0; mm < 3; ++mm) {
    float* op = (mm == 0) ? q : (mm == 1) ? k : v;
#pragma unroll
    for (int hc = 0; hc < 4; ++hc)
#pragma unroll
      for (int r = 0; r < 4; ++r) {
        long row = row0 + w * 16 + g * 4 + r;   // C/D: row=(lane>>4)*4+reg
        op[row * H + hc * 16 + l15] = acc[mm][hc][r];
      }
  }
}

// ---------- causal flash attention, bf16 MFMA ----------
// Q-tile 64 (wave owns 16 rows), K-tile 64. grid = Bn * S/64 = 256.
__global__ __launch_bounds__(256) void attn_kernel(
    const float* __restrict__ q, const float* __restrict__ k,
    const float* __restrict__ v, float* __restrict__ out) {
  __shared__ unsigned short qs[64][72];   // [qrow][h]
  __shared__ unsigned short ks[64][72];   // [key][h]   (QK^T B: k=h contiguous)
  __shared__ unsigned short vt[64][72];   // [h][key]   (PV  B: k=key contiguous)
  __shared__ unsigned short pl[64][72];   // [qrow][key] (PV A, per-wave rows)
  const int t = threadIdx.x;
  const int w = t >> 6, lane = t & 63, l15 = lane & 15, g = lane >> 4;
  const int qt = blockIdx.x & 31, b = blockIdx.x >> 5;
  const float* qb = q + ((long)b * S + qt * 64) * H;
  const float* kb = k + (long)b * S * H;
  const float* vb = v + (long)b * S * H;

  // stage Q (pre-scaled by E^-0.5), read A-frags once
#pragma unroll
  for (int it = 0; it < 4; ++it) {
    int idx = t + it * 256;
    float4 f = ((const float4*)(qb + (long)(idx >> 4) * H))[idx & 15];
    f.x *= SCALE; f.y *= SCALE; f.z *= SCALE; f.w *= SCALE;
    *(ushort4*)&qs[idx >> 4][(idx & 15) * 4] = f4bf(f);
  }
  __syncthreads();
  short8 aq[2];
  aq[0] = *(const short8*)&qs[w * 16 + l15][g * 8];
  aq[1] = *(const short8*)&qs[w * 16 + l15][32 + g * 8];

  f32x4 O[4];
  float m_[4], l_[4];
#pragma unroll
  for (int c = 0; c < 4; ++c) O[c] = f32x4{0.f, 0.f, 0.f, 0.f};
#pragma unroll
  for (int r = 0; r < 4; ++r) { m_[r] = -1e30f; l_[r] = 0.f; }

  float4 pk[4], pv[4];
  // prologue: tile 0 -> regs -> LDS
#pragma unroll
  for (int it = 0; it < 4; ++it) {
    int idx = t + it * 256;
    pk[it] = ((const float4*)(kb + (long)(idx >> 4) * H))[idx & 15];
    pv[it] = ((const float4*)(vb + (long)(idx >> 4) * H))[idx & 15];
  }
#pragma unroll
  for (int it = 0; it < 4; ++it) {
    int idx = t + it * 256;
    int r = idx >> 4, c4 = idx & 15;
    *(ushort4*)&ks[r][c4 * 4] = f4bf(pk[it]);
    vt[c4 * 4 + 0][r] = f2bf(pv[it].x);   // transpose scatter
    vt[c4 * 4 + 1][r] = f2bf(pv[it].y);
    vt[c4 * 4 + 2][r] = f2bf(pv[it].z);
    vt[c4 * 4 + 3][r] = f2bf(pv[it].w);
  }

  for (int kt = 0; kt <= qt; ++kt) {
    __syncthreads();                      // staged K/V visible
    if (kt < qt) {                        // prefetch next tile
      const float* kp = kb + (long)(kt + 1) * 64 * H;
      const float* vp = vb + (long)(kt + 1) * 64 * H;
#pragma unroll
      for (int it = 0; it < 4; ++it) {
        int idx = t + it * 256;
        pk[it] = ((const float4*)(kp + (long)(idx >> 4) * H))[idx & 15];
        pv[it] = ((const float4*)(vp + (long)(idx >> 4) * H))[idx & 15];
      }
    }
    // ---- S = Q K^T ----
    f32x4 sc[4];
#pragma unroll
    for (int c = 0; c < 4; ++c) sc[c] = f32x4{0.f, 0.f, 0.f, 0.f};
#pragma unroll
    for (int c = 0; c < 4; ++c)
#pragma unroll
      for (int kh = 0; kh < 2; ++kh) {
        short8 bk = *(const short8*)&ks[c * 16 + l15][kh * 32 + g * 8];
        sc[c] = __builtin_amdgcn_mfma_f32_16x16x32_bf16(aq[kh], bk, sc[c], 0, 0, 0);
      }
    if (kt == qt) {                       // only diagonal tile masks
#pragma unroll
      for (int c = 0; c < 4; ++c)
#pragma unroll
        for (int r = 0; r < 4; ++r)
          if (c * 16 + l15 > w * 16 + g * 4 + r) sc[c][r] = -1e30f;
    }
    // ---- online softmax (row = (lane>>4)*4 + r; reduce over 16 lanes) ----
    float al[4];
#pragma unroll
    for (int r = 0; r < 4; ++r) {
      float mx = fmaxf(fmaxf(sc[0][r], sc[1][r]), fmaxf(sc[2][r], sc[3][r]));
#pragma unroll
      for (int off = 8; off > 0; off >>= 1) mx = fmaxf(mx, __shfl_xor(mx, off));
      float mn = fmaxf(m_[r], mx);
      al[r] = exp2f((m_[r] - mn) * LOG2E);
      float sum = 0.f;
#pragma unroll
      for (int c = 0; c < 4; ++c) {
        float p = exp2f((sc[c][r] - mn) * LOG2E);
        sc[c][r] = p;
        sum += p;
      }
#pragma unroll
      for (int off = 8; off > 0; off >>= 1) sum += __shfl_xor(sum, off);
      l_[r] = l_[r] * al[r] + sum;
      m_[r] = mn;
    }
    // ---- P -> LDS (same-wave rows: no barrier needed), rescale O ----
#pragma unroll
    for (int c = 0; c < 4; ++c)
#pragma unroll
      for (int r = 0; r < 4; ++r)
        pl[w * 16 + g * 4 + r][c * 16 + l15] = f2bf(sc[c][r]);
#pragma unroll
    for (int c = 0; c < 4; ++c)
#pragma unroll
      for (int r = 0; r < 4; ++r) O[c][r] *= al[r];
    // ---- O += P V ----
#pragma unroll
    for (int kh = 0; kh < 2; ++kh) {
      short8 ap = *(const short8*)&pl[w * 16 + l15][kh * 32 + g * 8];
#pragma unroll
      for (int c = 0; c < 4; ++c) {
        short8 bv = *(const short8*)&vt[c * 16 + l15][kh * 32 + g * 8];
        O[c] = __builtin_amdgcn_mfma_f32_16x16x32_bf16(ap, bv, O[c], 0, 0, 0);
      }
    }
    __syncthreads();                      // all reads done; safe to overwrite
    if (kt < qt) {
#pragma unroll
      for (int it = 0; it < 4; ++it) {
        int idx = t + it * 256;
        int r = idx >> 4, c4 = idx & 15;
        *(ushort4*)&ks[r][c4 * 4] = f4bf(pk[it]);
        vt[c4 * 4 + 0][r] = f2bf(pv[it].x);
        vt[c4 * 4 + 1][r] = f2bf(pv[it].y);
        vt[c4 * 4 + 2][r] = f2bf(pv[it].z);
        vt[c4 * 4 + 3][r] = f2bf(pv[it].w);
      }
    }
  }
#pragma unroll
  for (int r = 0; r < 4; ++r) {
    float inv = 1.0f / l_[r];
    long row = (long)b * S + qt * 64 + w * 16 + g * 4 + r;
#pragma unroll
    for (int c = 0; c < 4; ++c)
      out[row * H + c * 16 + l15] = O[c][r] * inv;
  }
}

extern "C" void kernel_launch(void* const* d_in, const int* in_sizes, int n_in,
                              void* d_out, int out_size, void* d_ws, size_t ws_size,
                              hipStream_t stream) {
  const float* x  = (const float*)d_in[0];
  const float* Wq = (const float*)d_in[1];
  const float* Wk = (const float*)d_in[2];
  const float* Wv = (const float*)d_in[3];
  float* outp = (float*)d_out;
  unsigned short* WT3 = (unsigned short*)d_ws;            // 384 KB
  float* q = (float*)((char*)d_ws + 512 * 1024);          // 3 x 4 MB
  float* k = q + (size_t)Bn * S * H;
  float* v = k + (size_t)Bn * S * H;
  wtrans_kernel<<<dim3(48), dim3(256), 0, stream>>>(Wq, Wk, Wv, WT3);
  qkv_kernel<<<dim3((Bn * S) / 64), dim3(256), 0, stream>>>(x, WT3, q, k, v);
  attn_kernel<<<dim3(Bn * (S / 64)), dim3(256), 0, stream>>>(q, k, v, outp);
}